// Round 7
// baseline (133.867 us; speedup 1.0000x reference)
//
#include <hip/hip_runtime.h>

#define NTOT 1024
#define CIN  256
#define BATCH 16
#define NH   8
#define KD   16
#define DV   32
#define L2E  1.44269504088896340736f

typedef unsigned short u16;
typedef unsigned int   u32;
typedef __attribute__((ext_vector_type(2)))  _Float16 f16x2;
typedef __attribute__((ext_vector_type(8)))  _Float16 f16x8;
typedef __attribute__((ext_vector_type(16))) float    f32x16;

__device__ inline f16x8 as_f16x8(uint4 u) { return __builtin_bit_cast(f16x8, u); }
__device__ inline f16x2 as_f16x2(u32 u)   { return __builtin_bit_cast(f16x2, u); }
__device__ inline u32 pkrtz(float a, float b) {
  return __builtin_bit_cast(u32, __builtin_amdgcn_cvt_pkrtz(a, b));
}
__device__ inline u16 f2h(float x) {
  return __builtin_bit_cast(u16, (_Float16)x);
}
__device__ inline float fexp2(float x) {
#if __has_builtin(__builtin_amdgcn_exp2f)
  return __builtin_amdgcn_exp2f(x);              // raw v_exp_f32
#else
  float r; asm("v_exp_f32 %0, %1" : "=v"(r) : "v"(x)); return r;
#endif
}
__device__ inline float dot2acc(u32 p2, float c) {
#if __has_builtin(__builtin_amdgcn_fdot2)
  const f16x2 one2 = __builtin_bit_cast(f16x2, (u32)0x3C003C00u);
  return __builtin_amdgcn_fdot2(as_f16x2(p2), one2, c, false);
#else
  const f16x2 v = as_f16x2(p2);
  return c + (float)v[0] + (float)v[1];
#endif
}

// ---------------------------------------------------------------------------
// Weight prep: fp32 -> fp16, BN scale folded; Q rows (and bias) x log2(e).
// ---------------------------------------------------------------------------
__global__ __launch_bounds__(64) void prep_weights(
    const float* __restrict__ wq, const float* __restrict__ sq, const float* __restrict__ bq,
    const float* __restrict__ wk, const float* __restrict__ sk, const float* __restrict__ bk,
    const float* __restrict__ wv, const float* __restrict__ sv, const float* __restrict__ bv,
    const float* __restrict__ wp, const float* __restrict__ sp, const float* __restrict__ bp,
    u16* __restrict__ wqkv, u16* __restrict__ wph, float* __restrict__ ball)
{
  const int row = blockIdx.x;  // 0..767
  const int t = threadIdx.x;
  const float* src; u16* dst; float sc, bi;
  if (row < 128)      { src = wq + (size_t)row*CIN;       sc = sq[row]*L2E;     bi = bq[row]*L2E;     dst = wqkv + (size_t)row*CIN; }
  else if (row < 256) { src = wk + (size_t)(row-128)*CIN; sc = sk[row-128];     bi = bk[row-128];     dst = wqkv + (size_t)row*CIN; }
  else if (row < 512) { src = wv + (size_t)(row-256)*CIN; sc = sv[row-256];     bi = bv[row-256];     dst = wqkv + (size_t)row*CIN; }
  else                { src = wp + (size_t)(row-512)*CIN; sc = sp[row-512];     bi = bp[row-512];     dst = wph + (size_t)(row-512)*CIN; }
  const float4 v = *(const float4*)&src[t*4];
  ushort4 r;
  r.x = f2h(v.x*sc); r.y = f2h(v.y*sc); r.z = f2h(v.z*sc); r.w = f2h(v.w*sc);
  *(ushort4*)&dst[t*4] = r;
  if (t == 0) ball[row] = bi;
}

// ---------------------------------------------------------------------------
// QKV conv GEMM reading x (fp32) DIRECTLY: transpose + fp16 convert happens
// during B-LDS staging (scattered b16 writes; XOR swizzle keeps b128 frag
// reads conflict-free).  BM=128, BN=128, 4 waves 2x2.  Epilogue scatters to
// attention-native layouts: q_t [bh][n][16], k_t [bh][plane2][m][8],
// v_h [bh][mb16][g2][d32][8].
// ---------------------------------------------------------------------------
__global__ __launch_bounds__(256) void conv_qkv(
    const float* __restrict__ X, const u16* __restrict__ Wh,
    const float* __restrict__ ball,
    u16* __restrict__ q_t, u16* __restrict__ k_t, u16* __restrict__ v_h)
{
  __shared__ u16 A_lds[128 * 64];
  __shared__ u16 B_lds[128 * 64];
  const int t    = threadIdx.x;
  const int lane = t & 63;
  const int w    = t >> 6;
  const int wm = w >> 1, wn = w & 1;
  const int g = lane >> 5, nl = lane & 31;
  const int n0 = blockIdx.x * 128;
  const int m0 = blockIdx.y * 128;
  const int b  = blockIdx.z;

  f32x16 acc[2][2] = {};

  for (int c0 = 0; c0 < CIN; c0 += 64) {
    // A: weights fp16, b128 writes
    #pragma unroll
    for (int r = 0; r < 4; ++r) {
      const int idx = t + r*256, row = idx >> 3, ch = idx & 7;
      *(uint4*)&A_lds[row*64 + ((ch ^ (row&7))*8)] =
          *(const uint4*)&Wh[(size_t)(m0+row)*CIN + c0 + ch*8];
    }
    // B: x fp32 rows (c-major), convert + transpose into [n][c] swizzled
    #pragma unroll
    for (int r = 0; r < 8; ++r) {
      const int idx = t + r*256;
      const int c  = idx >> 5;          // 0..63
      const int nq = (idx & 31) * 4;    // 0..124
      const float4 v = *(const float4*)&X[((size_t)b*CIN + c0 + c)*NTOT + n0 + nq];
      const int ch = c >> 3, cl = c & 7;
      B_lds[(nq+0)*64 + ((ch ^ ((nq+0)&7))*8) + cl] = f2h(v.x);
      B_lds[(nq+1)*64 + ((ch ^ ((nq+1)&7))*8) + cl] = f2h(v.y);
      B_lds[(nq+2)*64 + ((ch ^ ((nq+2)&7))*8) + cl] = f2h(v.z);
      B_lds[(nq+3)*64 + ((ch ^ ((nq+3)&7))*8) + cl] = f2h(v.w);
    }
    __syncthreads();
    #pragma unroll
    for (int ks = 0; ks < 4; ++ks) {
      const int ch = 2*ks + g;
      f16x8 a[2], bb[2];
      #pragma unroll
      for (int fi = 0; fi < 2; ++fi) {
        const int row = wm*64 + fi*32 + nl;
        a[fi] = as_f16x8(*(const uint4*)&A_lds[row*64 + ((ch ^ (row&7))*8)]);
      }
      #pragma unroll
      for (int fj = 0; fj < 2; ++fj) {
        const int row = wn*64 + fj*32 + nl;
        bb[fj] = as_f16x8(*(const uint4*)&B_lds[row*64 + ((ch ^ (row&7))*8)]);
      }
      #pragma unroll
      for (int fi = 0; fi < 2; ++fi)
        #pragma unroll
        for (int fj = 0; fj < 2; ++fj)
          acc[fi][fj] = __builtin_amdgcn_mfma_f32_32x32x16_f16(a[fi], bb[fj], acc[fi][fj], 0, 0, 0);
    }
    __syncthreads();
  }

  #pragma unroll
  for (int fi = 0; fi < 2; ++fi) {
    #pragma unroll
    for (int fj = 0; fj < 2; ++fj) {
      const int n = n0 + wn*64 + fj*32 + nl;
      #pragma unroll
      for (int q = 0; q < 4; ++q) {
        const int ob = m0 + wm*64 + fi*32 + 8*q + 4*g;   // wave-uniform
        const float v0 = acc[fi][fj][4*q+0] + ball[ob+0];
        const float v1 = acc[fi][fj][4*q+1] + ball[ob+1];
        const float v2 = acc[fi][fj][4*q+2] + ball[ob+2];
        const float v3 = acc[fi][fj][4*q+3] + ball[ob+3];
        if (ob < 128) {                       // Q rows
          const int h = ob >> 4, k0 = ob & 15;
          ushort4 r; r.x = f2h(v0); r.y = f2h(v1); r.z = f2h(v2); r.w = f2h(v3);
          *(ushort4*)&q_t[(((size_t)b*NH + h)*NTOT + n)*KD + k0] = r;
        } else if (ob < 256) {                // K rows -> plane layout
          const int oo = ob - 128;
          const int h = oo >> 4, k0 = oo & 15;
          const int plane = k0 >> 3, j0 = k0 & 7;
          ushort4 r; r.x = f2h(v0); r.y = f2h(v1); r.z = f2h(v2); r.w = f2h(v3);
          *(ushort4*)&k_t[((((size_t)b*NH + h)*2 + plane)*NTOT + n)*8 + j0] = r;
        } else {                              // V rows -> permuted layout
          const int oo = ob - 256;
          const int h = oo >> 5, d0 = oo & 31;
          const int mb = n >> 4, loc = n & 15;
          const int g2 = (loc >> 2) & 1;
          const int j  = (loc & 3) + ((loc >> 3) << 2);
          u16* vp = v_h + (((((size_t)b*NH + h)*64 + mb)*2 + g2)*32 + d0)*8 + j;
          vp[0*8] = f2h(v0);
          vp[1*8] = f2h(v1);
          vp[2*8] = f2h(v2);
          vp[3*8] = f2h(v3);
        }
      }
    }
  }
}

// ---------------------------------------------------------------------------
// Out-proj fp16 MFMA GEMM (R5 structure, dbuf): BM=128, BN=64, fp32 out.
// ---------------------------------------------------------------------------
__global__ __launch_bounds__(256) void conv_out(
    const u16* __restrict__ Wh, const u16* __restrict__ Bt,
    const float* __restrict__ ball, float* __restrict__ outp)
{
  __shared__ u16 A_lds[2][128 * 64];
  __shared__ u16 B_lds[2][64 * 64];
  const int t    = threadIdx.x;
  const int lane = t & 63;
  const int w    = t >> 6;
  const int wm = w >> 1, wn = w & 1;
  const int g = lane >> 5, nl = lane & 31;
  const int n0 = blockIdx.x * 64;
  const int m0 = blockIdx.y * 128;
  const int b  = blockIdx.z;

  f32x16 acc[2][1] = {};
  uint4 rA[4], rB[2];

  #pragma unroll
  for (int r = 0; r < 4; ++r) {
    const int idx = t + r*256, row = idx >> 3, ch = idx & 7;
    rA[r] = *(const uint4*)&Wh[(size_t)(m0+row)*CIN + ch*8];
  }
  #pragma unroll
  for (int r = 0; r < 2; ++r) {
    const int idx = t + r*256, row = idx >> 3, ch = idx & 7;
    rB[r] = *(const uint4*)&Bt[((size_t)b*NTOT + n0 + row)*CIN + ch*8];
  }
  #pragma unroll
  for (int r = 0; r < 4; ++r) {
    const int idx = t + r*256, row = idx >> 3, ch = idx & 7;
    *(uint4*)&A_lds[0][row*64 + ((ch ^ (row&7))*8)] = rA[r];
  }
  #pragma unroll
  for (int r = 0; r < 2; ++r) {
    const int idx = t + r*256, row = idx >> 3, ch = idx & 7;
    *(uint4*)&B_lds[0][row*64 + ((ch ^ (row&7))*8)] = rB[r];
  }
  __syncthreads();

  for (int it = 0; it < 4; ++it) {
    const int cur = it & 1;
    if (it < 3) {
      const int c0 = (it+1)*64;
      #pragma unroll
      for (int r = 0; r < 4; ++r) {
        const int idx = t + r*256, row = idx >> 3, ch = idx & 7;
        rA[r] = *(const uint4*)&Wh[(size_t)(m0+row)*CIN + c0 + ch*8];
      }
      #pragma unroll
      for (int r = 0; r < 2; ++r) {
        const int idx = t + r*256, row = idx >> 3, ch = idx & 7;
        rB[r] = *(const uint4*)&Bt[((size_t)b*NTOT + n0 + row)*CIN + c0 + ch*8];
      }
    }
    #pragma unroll
    for (int ks = 0; ks < 4; ++ks) {
      const int ch = 2*ks + g;
      f16x8 a[2], bb;
      #pragma unroll
      for (int fi = 0; fi < 2; ++fi) {
        const int row = wm*64 + fi*32 + nl;
        a[fi] = as_f16x8(*(const uint4*)&A_lds[cur][row*64 + ((ch ^ (row&7))*8)]);
      }
      {
        const int row = wn*32 + nl;
        bb = as_f16x8(*(const uint4*)&B_lds[cur][row*64 + ((ch ^ (row&7))*8)]);
      }
      #pragma unroll
      for (int fi = 0; fi < 2; ++fi)
        acc[fi][0] = __builtin_amdgcn_mfma_f32_32x32x16_f16(a[fi], bb, acc[fi][0], 0, 0, 0);
    }
    if (it < 3) {
      #pragma unroll
      for (int r = 0; r < 4; ++r) {
        const int idx = t + r*256, row = idx >> 3, ch = idx & 7;
        *(uint4*)&A_lds[cur^1][row*64 + ((ch ^ (row&7))*8)] = rA[r];
      }
      #pragma unroll
      for (int r = 0; r < 2; ++r) {
        const int idx = t + r*256, row = idx >> 3, ch = idx & 7;
        *(uint4*)&B_lds[cur^1][row*64 + ((ch ^ (row&7))*8)] = rB[r];
      }
      __syncthreads();
    }
  }

  #pragma unroll
  for (int fi = 0; fi < 2; ++fi) {
    const int n = n0 + wn*32 + nl;
    #pragma unroll
    for (int q = 0; q < 4; ++q) {
      const int ob = m0 + wm*64 + fi*32 + 8*q + 4*g;
      float* op = outp + ((size_t)b*CIN + ob)*NTOT + n;
      op[0*NTOT] = acc[fi][0][4*q+0] + ball[ob+0];
      op[1*NTOT] = acc[fi][0][4*q+1] + ball[ob+1];
      op[2*NTOT] = acc[fi][0][4*q+2] + ball[ob+2];
      op[3*NTOT] = acc[fi][0][4*q+3] + ball[ob+3];
    }
  }
}

// ---------------------------------------------------------------------------
// fp16 MFMA attention, exp2 domain, no max-tracking, shuffle-free P->PV.
// R5 structure (16 waves = one (b,h) x 512 queries), rebuilt as a fully
// unrolled 2-step rotation: disjoint A/B register sets, no rotate-copies,
// all LDS offsets fold to immediates.  XCD swizzle co-locates both halves
// of each bh on one XCD.  setprio(1) on PV MFMAs only.
// ---------------------------------------------------------------------------
__global__ __launch_bounds__(1024) void attn_mfma(
    const u16* __restrict__ Qt,  // [bh][n][16] fp16 (x log2e folded)
    const u16* __restrict__ Kt,  // [bh][plane2][m][8] fp16
    const u16* __restrict__ Vt,  // [bh][mb16][g2][d32][8] fp16
    u16* __restrict__ Ot)        // [b][n][256c] fp16 (relu'd)
{
  __shared__ u16 K_lds[2*NTOT*8];   // 32 KB
  __shared__ u16 V_lds[4096*8];     // 64 KB
  const int t    = threadIdx.x;
  const int lane = t & 63;
  const int wave = t >> 6;
  const int bid  = blockIdx.x;
  const int wgid = (bid & 7)*32 + (bid >> 3);   // XCD swizzle (256 = 8*32)
  const int bh   = wgid >> 1;
  const int half = wgid & 1;
  const int g = lane >> 5, nl = lane & 31;
  const int n0 = half*512 + wave*32;

  const u16* Kh = Kt + (size_t)bh*(2*NTOT*8);
  const u16* Vh = Vt + (size_t)bh*(4096*8);
  const u16* Qh = Qt + (size_t)bh*(NTOT*KD);

  #pragma unroll
  for (int r = 0; r < 2; ++r) {
    const int uu = r*1024 + t;
    *(uint4*)&K_lds[uu*8] = *(const uint4*)&Kh[uu*8];
  }
  #pragma unroll
  for (int r = 0; r < 4; ++r) {
    const int uu = r*1024 + t;
    *(uint4*)&V_lds[uu*8] = *(const uint4*)&Vh[uu*8];
  }

  const f16x8 qf = as_f16x8(*(const uint4*)&Qh[(size_t)(n0+nl)*KD + g*8]);
  __syncthreads();

  const f32x16 fzero = {};
  f32x16 acc = {};
  float l0 = 0.f, l1 = 0.f, l2 = 0.f, l3 = 0.f;
  const char* Kb = (const char*)K_lds + g*16384 + nl*16;  // + step*512
  const char* Vb = (const char*)V_lds + g*512   + nl*16;  // + step*2048 (+1024)

  // prologue: steps 0/1 in flight
  f16x8 kfA = as_f16x8(*(const uint4*)(Kb));
  f16x8 kfB = as_f16x8(*(const uint4*)(Kb + 512));
  f32x16 sA = __builtin_amdgcn_mfma_f32_32x32x16_f16(kfA, qf, fzero, 0, 0, 0);
  f32x16 sB = __builtin_amdgcn_mfma_f32_32x32x16_f16(kfB, qf, fzero, 0, 0, 0);
  kfA = as_f16x8(*(const uint4*)(Kb + 1024));   // K for step 2
  kfB = as_f16x8(*(const uint4*)(Kb + 1536));   // K for step 3
  uint4 vaA0 = *(const uint4*)(Vb);
  uint4 vaA1 = *(const uint4*)(Vb + 1024);
  uint4 vaB0 = *(const uint4*)(Vb + 2048);
  uint4 vaB1 = *(const uint4*)(Vb + 3072);

  #pragma unroll
  for (int i = 0; i < 16; ++i) {
    // ===== even step e = 2i: consume sA / vaA =====
    {
      float p[16];
      #pragma unroll
      for (int r = 0; r < 16; ++r) p[r] = fexp2(sA[r]);
      uint4 pb0, pb1;
      pb0.x = pkrtz(p[0],  p[1]);  pb0.y = pkrtz(p[2],  p[3]);
      pb0.z = pkrtz(p[4],  p[5]);  pb0.w = pkrtz(p[6],  p[7]);
      pb1.x = pkrtz(p[8],  p[9]);  pb1.y = pkrtz(p[10], p[11]);
      pb1.z = pkrtz(p[12], p[13]); pb1.w = pkrtz(p[14], p[15]);
      l0 = dot2acc(pb0.x, l0); l1 = dot2acc(pb0.y, l1);
      l2 = dot2acc(pb0.z, l2); l3 = dot2acc(pb0.w, l3);
      l0 = dot2acc(pb1.x, l0); l1 = dot2acc(pb1.y, l1);
      l2 = dot2acc(pb1.z, l2); l3 = dot2acc(pb1.w, l3);
      if (i < 15) sA = __builtin_amdgcn_mfma_f32_32x32x16_f16(kfA, qf, fzero, 0, 0, 0);   // step 2i+2
      if (i < 14) kfA = as_f16x8(*(const uint4*)(Kb + (2*i+4)*512));                      // K step 2i+4
      __builtin_amdgcn_s_setprio(1);
      acc = __builtin_amdgcn_mfma_f32_32x32x16_f16(as_f16x8(vaA0), as_f16x8(pb0), acc, 0, 0, 0);
      acc = __builtin_amdgcn_mfma_f32_32x32x16_f16(as_f16x8(vaA1), as_f16x8(pb1), acc, 0, 0, 0);
      __builtin_amdgcn_s_setprio(0);
      if (i < 15) {
        vaA0 = *(const uint4*)(Vb + (2*i+2)*2048);
        vaA1 = *(const uint4*)(Vb + (2*i+2)*2048 + 1024);
      }
    }
    // ===== odd step o = 2i+1: consume sB / vaB =====
    {
      float p[16];
      #pragma unroll
      for (int r = 0; r < 16; ++r) p[r] = fexp2(sB[r]);
      uint4 pb0, pb1;
      pb0.x = pkrtz(p[0],  p[1]);  pb0.y = pkrtz(p[2],  p[3]);
      pb0.z = pkrtz(p[4],  p[5]);  pb0.w = pkrtz(p[6],  p[7]);
      pb1.x = pkrtz(p[8],  p[9]);  pb1.y = pkrtz(p[10], p[11]);
      pb1.z = pkrtz(p[12], p[13]); pb1.w = pkrtz(p[14], p[15]);
      l0 = dot2acc(pb0.x, l0); l1 = dot2acc(pb0.y, l1);
      l2 = dot2acc(pb0.z, l2); l3 = dot2acc(pb0.w, l3);
      l0 = dot2acc(pb1.x, l0); l1 = dot2acc(pb1.y, l1);
      l2 = dot2acc(pb1.z, l2); l3 = dot2acc(pb1.w, l3);
      if (i < 15) sB = __builtin_amdgcn_mfma_f32_32x32x16_f16(kfB, qf, fzero, 0, 0, 0);   // step 2i+3
      if (i < 14) kfB = as_f16x8(*(const uint4*)(Kb + (2*i+5)*512));                      // K step 2i+5
      __builtin_amdgcn_s_setprio(1);
      acc = __builtin_amdgcn_mfma_f32_32x32x16_f16(as_f16x8(vaB0), as_f16x8(pb0), acc, 0, 0, 0);
      acc = __builtin_amdgcn_mfma_f32_32x32x16_f16(as_f16x8(vaB1), as_f16x8(pb1), acc, 0, 0, 0);
      __builtin_amdgcn_s_setprio(0);
      if (i < 15) {
        vaB0 = *(const uint4*)(Vb + (2*i+3)*2048);
        vaB1 = *(const uint4*)(Vb + (2*i+3)*2048 + 1024);
      }
    }
  }

  const float lp = (l0 + l1) + (l2 + l3);
  const float lt = lp + __shfl_xor(lp, 32);
  const float rl = 1.0f / lt;
  const int b = bh >> 3, h = bh & 7;
  u16* op = Ot + ((size_t)b*NTOT + n0 + nl)*CIN + h*DV;
  #pragma unroll
  for (int q = 0; q < 4; ++q) {
    const float v0 = fmaxf(acc[4*q+0]*rl, 0.f);
    const float v1 = fmaxf(acc[4*q+1]*rl, 0.f);
    const float v2 = fmaxf(acc[4*q+2]*rl, 0.f);
    const float v3 = fmaxf(acc[4*q+3]*rl, 0.f);
    uint2 pk; pk.x = pkrtz(v0, v1); pk.y = pkrtz(v2, v3);
    *(uint2*)&op[8*q + 4*g] = pk;   // c = h*32 + 8q + 4g + {0..3}
  }
}

// ---------------------------------------------------------------------------
extern "C" void kernel_launch(void* const* d_in, const int* in_sizes, int n_in,
                              void* d_out, int out_size, void* d_ws, size_t ws_size,
                              hipStream_t stream) {
  const float* x  = (const float*)d_in[0];
  const float* wq = (const float*)d_in[1];
  const float* sq = (const float*)d_in[2];
  const float* bq = (const float*)d_in[3];
  const float* wk = (const float*)d_in[4];
  const float* sk = (const float*)d_in[5];
  const float* bk = (const float*)d_in[6];
  const float* wv = (const float*)d_in[7];
  const float* sv = (const float*)d_in[8];
  const float* bv = (const float*)d_in[9];
  const float* wp = (const float*)d_in[10];
  const float* sp = (const float*)d_in[11];
  const float* bp = (const float*)d_in[12];
  float* out = (float*)d_out;

  // ws: o_t @0 (8MB) | q_t @8M | k_t @12M | v_h @16M (8MB) | wqkv @24M | wph | ball
  char* ws = (char*)d_ws;
  u16*   o_t  = (u16*)(ws);
  u16*   q_t  = (u16*)(ws + (8u  << 20));
  u16*   k_t  = (u16*)(ws + (12u << 20));
  u16*   v_h  = (u16*)(ws + (16u << 20));
  u16*   wqkv = (u16*)(ws + (24u << 20));
  u16*   wph  = (u16*)(ws + (24u << 20) + (256u << 10));
  float* ball = (float*)(ws + (24u << 20) + (384u << 10));

  prep_weights<<<dim3(768), dim3(64), 0, stream>>>(
      wq, sq, bq, wk, sk, bk, wv, sv, bv, wp, sp, bp, wqkv, wph, ball);
  conv_qkv<<<dim3(8, 4, 16), dim3(256), 0, stream>>>(
      x, wqkv, ball, q_t, k_t, v_h);
  attn_mfma<<<dim3(256), dim3(1024), 0, stream>>>(q_t, k_t, v_h, o_t);
  conv_out<<<dim3(16, 2, 16), dim3(256), 0, stream>>>(
      wph, o_t, ball + 512, out);
}

// Round 8
// 102.622 us; speedup vs baseline: 1.3045x; 1.3045x over previous
//
#include <hip/hip_runtime.h>

#define NTOT 1024
#define CIN  256
#define BATCH 16
#define NH   8
#define KD   16
#define DV   32
#define L2E  1.44269504088896340736f

typedef unsigned short u16;
typedef unsigned int   u32;
typedef __attribute__((ext_vector_type(2)))  _Float16 f16x2;
typedef __attribute__((ext_vector_type(8)))  _Float16 f16x8;
typedef __attribute__((ext_vector_type(16))) float    f32x16;

__device__ inline f16x8 as_f16x8(uint4 u) { return __builtin_bit_cast(f16x8, u); }
__device__ inline f16x2 as_f16x2(u32 u)   { return __builtin_bit_cast(f16x2, u); }
__device__ inline u32 pkrtz(float a, float b) {
  return __builtin_bit_cast(u32, __builtin_amdgcn_cvt_pkrtz(a, b));
}
__device__ inline u16 f2h(float x) {
  return __builtin_bit_cast(u16, (_Float16)x);
}
__device__ inline float fexp2(float x) {
#if __has_builtin(__builtin_amdgcn_exp2f)
  return __builtin_amdgcn_exp2f(x);              // raw v_exp_f32
#else
  float r; asm("v_exp_f32 %0, %1" : "=v"(r) : "v"(x)); return r;
#endif
}
__device__ inline float dot2acc(u32 p2, float c) {
#if __has_builtin(__builtin_amdgcn_fdot2)
  const f16x2 one2 = __builtin_bit_cast(f16x2, (u32)0x3C003C00u);
  return __builtin_amdgcn_fdot2(as_f16x2(p2), one2, c, false);
#else
  const f16x2 v = as_f16x2(p2);
  return c + (float)v[0] + (float)v[1];
#endif
}

// ---------------------------------------------------------------------------
// Fused prep: blocks [0,1024): x[b][c][n] fp32 -> x_t[b][n][c] fp16 (64x64
// LDS transpose).  Blocks [1024,1216): weight fp32->fp16 with BN scale folded
// (Q rows x log2e for exp2-domain softmax), 4 rows per block.
// ---------------------------------------------------------------------------
__global__ __launch_bounds__(256) void prep_fused(
    const float* __restrict__ X, u16* __restrict__ Xt,
    const float* __restrict__ wq, const float* __restrict__ sq, const float* __restrict__ bq,
    const float* __restrict__ wk, const float* __restrict__ sk, const float* __restrict__ bk,
    const float* __restrict__ wv, const float* __restrict__ sv, const float* __restrict__ bv,
    const float* __restrict__ wp, const float* __restrict__ sp, const float* __restrict__ bp,
    u16* __restrict__ wqkv, u16* __restrict__ wph, float* __restrict__ ball)
{
  __shared__ u16 T[64][64];
  const int bx = blockIdx.x;
  const int t  = threadIdx.x;
  if (bx < 1024) {
    const int n0 = (bx & 15) * 64;
    const int c0 = ((bx >> 4) & 3) * 64;
    const int b  = bx >> 6;
    #pragma unroll
    for (int rr = 0; rr < 4; ++rr) {
      const int c  = rr*16 + (t>>4);
      const int n4 = (t&15)*4;
      const float4 v = *(const float4*)&X[((size_t)b*CIN + c0 + c)*NTOT + n0 + n4];
      ushort4 r; r.x=f2h(v.x); r.y=f2h(v.y); r.z=f2h(v.z); r.w=f2h(v.w);
      *(ushort4*)&T[c][n4] = r;
    }
    __syncthreads();
    const int nl = t & 63;
    #pragma unroll
    for (int j = 0; j < 2; ++j) {
      const int oct = (t>>6)*2 + j;
      uint4 w;
      w.x = (u32)T[oct*8+0][nl] | ((u32)T[oct*8+1][nl] << 16);
      w.y = (u32)T[oct*8+2][nl] | ((u32)T[oct*8+3][nl] << 16);
      w.z = (u32)T[oct*8+4][nl] | ((u32)T[oct*8+5][nl] << 16);
      w.w = (u32)T[oct*8+6][nl] | ((u32)T[oct*8+7][nl] << 16);
      *(uint4*)&Xt[((size_t)b*NTOT + n0 + nl)*CIN + c0 + oct*8] = w;
    }
  } else {
    const int row = (bx - 1024)*4 + (t>>6);   // 0..767
    const int ln  = t & 63;
    const float* src; u16* dst; float sc, bi;
    if (row < 128)      { src = wq + (size_t)row*CIN;       sc = sq[row]*L2E;     bi = bq[row]*L2E;     dst = wqkv + (size_t)row*CIN; }
    else if (row < 256) { src = wk + (size_t)(row-128)*CIN; sc = sk[row-128];     bi = bk[row-128];     dst = wqkv + (size_t)row*CIN; }
    else if (row < 512) { src = wv + (size_t)(row-256)*CIN; sc = sv[row-256];     bi = bv[row-256];     dst = wqkv + (size_t)row*CIN; }
    else                { src = wp + (size_t)(row-512)*CIN; sc = sp[row-512];     bi = bp[row-512];     dst = wph + (size_t)(row-512)*CIN; }
    const float4 v = *(const float4*)&src[ln*4];
    ushort4 r;
    r.x = f2h(v.x*sc); r.y = f2h(v.y*sc); r.z = f2h(v.z*sc); r.w = f2h(v.w*sc);
    *(ushort4*)&dst[ln*4] = r;
    if (ln == 0) ball[row] = bi;
  }
}

// ---------------------------------------------------------------------------
// fp16 MFMA GEMM, BM=128, BN templated, 4 waves 2x2, double-buffered LDS
// (reg-staged).  MODE 0 epilogue -> attention-native layouts.  MODE 1 -> fp32.
// ---------------------------------------------------------------------------
template<int BN, int MODE>
__global__ __launch_bounds__(256) void conv_mfma(
    const u16* __restrict__ Wh, const u16* __restrict__ Bt,
    const float* __restrict__ ball,
    u16* __restrict__ q_t, u16* __restrict__ k_t, u16* __restrict__ v_h,
    float* __restrict__ outp)
{
  constexpr int FN = BN / 64;
  constexpr int NB = BN / 32;
  __shared__ u16 A_lds[2][128 * 64];
  __shared__ u16 B_lds[2][BN * 64];
  const int t    = threadIdx.x;
  const int lane = t & 63;
  const int w    = t >> 6;
  const int wm = w >> 1, wn = w & 1;
  const int g = lane >> 5, nl = lane & 31;
  const int n0 = blockIdx.x * BN;
  const int m0 = blockIdx.y * 128;
  const int b  = blockIdx.z;

  f32x16 acc[2][FN] = {};
  uint4 rA[4], rB[NB];

  #pragma unroll
  for (int r = 0; r < 4; ++r) {
    const int idx = t + r*256, row = idx >> 3, ch = idx & 7;
    rA[r] = *(const uint4*)&Wh[(size_t)(m0+row)*CIN + ch*8];
  }
  #pragma unroll
  for (int r = 0; r < NB; ++r) {
    const int idx = t + r*256, row = idx >> 3, ch = idx & 7;
    rB[r] = *(const uint4*)&Bt[((size_t)b*NTOT + n0 + row)*CIN + ch*8];
  }
  #pragma unroll
  for (int r = 0; r < 4; ++r) {
    const int idx = t + r*256, row = idx >> 3, ch = idx & 7;
    *(uint4*)&A_lds[0][row*64 + ((ch ^ (row&7))*8)] = rA[r];
  }
  #pragma unroll
  for (int r = 0; r < NB; ++r) {
    const int idx = t + r*256, row = idx >> 3, ch = idx & 7;
    *(uint4*)&B_lds[0][row*64 + ((ch ^ (row&7))*8)] = rB[r];
  }
  __syncthreads();

  for (int it = 0; it < 4; ++it) {
    const int cur = it & 1;
    if (it < 3) {
      const int c0 = (it+1)*64;
      #pragma unroll
      for (int r = 0; r < 4; ++r) {
        const int idx = t + r*256, row = idx >> 3, ch = idx & 7;
        rA[r] = *(const uint4*)&Wh[(size_t)(m0+row)*CIN + c0 + ch*8];
      }
      #pragma unroll
      for (int r = 0; r < NB; ++r) {
        const int idx = t + r*256, row = idx >> 3, ch = idx & 7;
        rB[r] = *(const uint4*)&Bt[((size_t)b*NTOT + n0 + row)*CIN + c0 + ch*8];
      }
    }
    #pragma unroll
    for (int ks = 0; ks < 4; ++ks) {
      const int ch = 2*ks + g;
      f16x8 a[2], bb[FN];
      #pragma unroll
      for (int fi = 0; fi < 2; ++fi) {
        const int row = wm*64 + fi*32 + nl;
        a[fi] = as_f16x8(*(const uint4*)&A_lds[cur][row*64 + ((ch ^ (row&7))*8)]);
      }
      #pragma unroll
      for (int fj = 0; fj < FN; ++fj) {
        const int row = wn*(BN/2) + fj*32 + nl;
        bb[fj] = as_f16x8(*(const uint4*)&B_lds[cur][row*64 + ((ch ^ (row&7))*8)]);
      }
      #pragma unroll
      for (int fi = 0; fi < 2; ++fi)
        #pragma unroll
        for (int fj = 0; fj < FN; ++fj)
          acc[fi][fj] = __builtin_amdgcn_mfma_f32_32x32x16_f16(a[fi], bb[fj], acc[fi][fj], 0, 0, 0);
    }
    if (it < 3) {
      #pragma unroll
      for (int r = 0; r < 4; ++r) {
        const int idx = t + r*256, row = idx >> 3, ch = idx & 7;
        *(uint4*)&A_lds[cur^1][row*64 + ((ch ^ (row&7))*8)] = rA[r];
      }
      #pragma unroll
      for (int r = 0; r < NB; ++r) {
        const int idx = t + r*256, row = idx >> 3, ch = idx & 7;
        *(uint4*)&B_lds[cur^1][row*64 + ((ch ^ (row&7))*8)] = rB[r];
      }
      __syncthreads();
    }
  }

  #pragma unroll
  for (int fi = 0; fi < 2; ++fi) {
    #pragma unroll
    for (int fj = 0; fj < FN; ++fj) {
      const int n = n0 + wn*(BN/2) + fj*32 + nl;
      #pragma unroll
      for (int q = 0; q < 4; ++q) {
        const int ob = m0 + wm*64 + fi*32 + 8*q + 4*g;   // wave-uniform
        const float v0 = acc[fi][fj][4*q+0] + ball[ob+0];
        const float v1 = acc[fi][fj][4*q+1] + ball[ob+1];
        const float v2 = acc[fi][fj][4*q+2] + ball[ob+2];
        const float v3 = acc[fi][fj][4*q+3] + ball[ob+3];
        if (MODE == 0) {
          if (ob < 128) {                       // Q rows
            const int h = ob >> 4, k0 = ob & 15;
            ushort4 r; r.x = f2h(v0); r.y = f2h(v1); r.z = f2h(v2); r.w = f2h(v3);
            *(ushort4*)&q_t[(((size_t)b*NH + h)*NTOT + n)*KD + k0] = r;
          } else if (ob < 256) {                // K rows -> plane layout
            const int oo = ob - 128;
            const int h = oo >> 4, k0 = oo & 15;
            const int plane = k0 >> 3, j0 = k0 & 7;
            ushort4 r; r.x = f2h(v0); r.y = f2h(v1); r.z = f2h(v2); r.w = f2h(v3);
            *(ushort4*)&k_t[((((size_t)b*NH + h)*2 + plane)*NTOT + n)*8 + j0] = r;
          } else {                              // V rows -> permuted layout
            const int oo = ob - 256;
            const int h = oo >> 5, d0 = oo & 31;
            const int mb = n >> 4, loc = n & 15;
            const int g2 = (loc >> 2) & 1;
            const int j  = (loc & 3) + ((loc >> 3) << 2);
            u16* vp = v_h + (((((size_t)b*NH + h)*64 + mb)*2 + g2)*32 + d0)*8 + j;
            vp[0*8] = f2h(v0);
            vp[1*8] = f2h(v1);
            vp[2*8] = f2h(v2);
            vp[3*8] = f2h(v3);
          }
        } else {
          float* op = outp + ((size_t)b*CIN + ob)*NTOT + n;
          op[0*NTOT] = v0; op[1*NTOT] = v1; op[2*NTOT] = v2; op[3*NTOT] = v3;
        }
      }
    }
  }
}

// ---------------------------------------------------------------------------
// fp16 MFMA attention, exp2 domain, no max-tracking, shuffle-free P->PV.
// OCCUPANCY build: LDS = 64 KB (K resident 32 KB; V streamed in two 32 KB
// phases of 512 keys each) -> 2 blocks/CU; VGPR forced <= 64 via
// __launch_bounds__(1024, 8) -> 8 waves/SIMD.  No s_next ILP pipeline (TLP
// replaces it; R7 showed the unrolled 2-deep version spills).  Block = 16
// waves = one (b,h) x 512 queries; XCD swizzle co-locates each bh's 2 blocks.
// ---------------------------------------------------------------------------
__global__ __launch_bounds__(1024, 8) void attn_mfma(
    const u16* __restrict__ Qt,  // [bh][n][16] fp16 (x log2e folded)
    const u16* __restrict__ Kt,  // [bh][plane2][m][8] fp16
    const u16* __restrict__ Vt,  // [bh][mb16][g2][d32][8] fp16
    u16* __restrict__ Ot)        // [b][n][256c] fp16 (relu'd)
{
  __shared__ u16 K_lds[2*NTOT*8];   // 32 KB  [plane][m][8]
  __shared__ u16 V_lds[2048*8];     // 32 KB  one 512-key phase
  const int t    = threadIdx.x;
  const int lane = t & 63;
  const int wave = t >> 6;
  const int bid  = blockIdx.x;
  const int wgid = (bid & 7)*32 + (bid >> 3);   // XCD swizzle (256 = 8*32)
  const int bh   = wgid >> 1;
  const int half = wgid & 1;
  const int g = lane >> 5, nl = lane & 31;
  const int n0 = half*512 + wave*32;

  const u16* Kh = Kt + (size_t)bh*(2*NTOT*8);
  const u16* Vh = Vt + (size_t)bh*(4096*8);
  const u16* Qh = Qt + (size_t)bh*(NTOT*KD);

  // stage K (full 32 KB) + V phase 0 (32 KB), linear reg-staged copies
  *(uint4*)&K_lds[t*8]          = *(const uint4*)&Kh[t*8];
  *(uint4*)&K_lds[(t+1024)*8]   = *(const uint4*)&Kh[(t+1024)*8];
  *(uint4*)&V_lds[t*8]          = *(const uint4*)&Vh[t*8];
  *(uint4*)&V_lds[(t+1024)*8]   = *(const uint4*)&Vh[(t+1024)*8];

  const f16x8 qf = as_f16x8(*(const uint4*)&Qh[(size_t)(n0+nl)*KD + g*8]);
  __syncthreads();

  const f32x16 fzero = {};
  f32x16 acc = {};
  float l0 = 0.f, l1 = 0.f;
  const char* Kbase = (const char*)K_lds + g*16384 + nl*16;  // + step*512
  const char* Vbase = (const char*)V_lds + g*512   + nl*16;  // + sl*2048 (+1024)

  #pragma unroll 1
  for (int ph = 0; ph < 2; ++ph) {
    const char* Kb = Kbase + ph*8192;    // 16 steps x 512 B
    #pragma unroll
    for (int sl = 0; sl < 16; ++sl) {
      const f16x8 kf = as_f16x8(*(const uint4*)(Kb + sl*512));
      const f32x16 s = __builtin_amdgcn_mfma_f32_32x32x16_f16(kf, qf, fzero, 0, 0, 0);

      // first half: m-slots 0..7
      uint4 pb0;
      {
        float p[8];
        #pragma unroll
        for (int r = 0; r < 8; ++r) p[r] = fexp2(s[r]);
        pb0.x = pkrtz(p[0], p[1]); pb0.y = pkrtz(p[2], p[3]);
        pb0.z = pkrtz(p[4], p[5]); pb0.w = pkrtz(p[6], p[7]);
        l0 = dot2acc(pb0.x, l0); l1 = dot2acc(pb0.y, l1);
        l0 = dot2acc(pb0.z, l0); l1 = dot2acc(pb0.w, l1);
      }
      // second half: m-slots 8..15
      uint4 pb1;
      {
        float p[8];
        #pragma unroll
        for (int r = 0; r < 8; ++r) p[r] = fexp2(s[8+r]);
        pb1.x = pkrtz(p[0], p[1]); pb1.y = pkrtz(p[2], p[3]);
        pb1.z = pkrtz(p[4], p[5]); pb1.w = pkrtz(p[6], p[7]);
        l0 = dot2acc(pb1.x, l0); l1 = dot2acc(pb1.y, l1);
        l0 = dot2acc(pb1.z, l0); l1 = dot2acc(pb1.w, l1);
      }

      const uint4 va0 = *(const uint4*)(Vbase + sl*2048);
      const uint4 va1 = *(const uint4*)(Vbase + sl*2048 + 1024);
      __builtin_amdgcn_s_setprio(1);
      acc = __builtin_amdgcn_mfma_f32_32x32x16_f16(as_f16x8(va0), as_f16x8(pb0), acc, 0, 0, 0);
      acc = __builtin_amdgcn_mfma_f32_32x32x16_f16(as_f16x8(va1), as_f16x8(pb1), acc, 0, 0, 0);
      __builtin_amdgcn_s_setprio(0);
    }
    if (ph == 0) {
      // swap in V phase 1 (keys 512..1023); barrier-bounded reg-stage
      __syncthreads();                      // all waves done reading phase 0
      const uint4 nv0 = *(const uint4*)&Vh[(2048 + t)*8];
      const uint4 nv1 = *(const uint4*)&Vh[(3072 + t)*8];
      *(uint4*)&V_lds[t*8]        = nv0;
      *(uint4*)&V_lds[(t+1024)*8] = nv1;
      __syncthreads();                      // phase 1 visible
    }
  }

  const float lp = l0 + l1;
  const float lt = lp + __shfl_xor(lp, 32);
  const float rl = 1.0f / lt;
  const int b = bh >> 3, h = bh & 7;
  u16* op = Ot + ((size_t)b*NTOT + n0 + nl)*CIN + h*DV;
  #pragma unroll
  for (int q = 0; q < 4; ++q) {
    const float v0 = fmaxf(acc[4*q+0]*rl, 0.f);
    const float v1 = fmaxf(acc[4*q+1]*rl, 0.f);
    const float v2 = fmaxf(acc[4*q+2]*rl, 0.f);
    const float v3 = fmaxf(acc[4*q+3]*rl, 0.f);
    uint2 pk; pk.x = pkrtz(v0, v1); pk.y = pkrtz(v2, v3);
    *(uint2*)&op[8*q + 4*g] = pk;   // c = h*32 + 8q + 4g + {0..3}
  }
}

// ---------------------------------------------------------------------------
extern "C" void kernel_launch(void* const* d_in, const int* in_sizes, int n_in,
                              void* d_out, int out_size, void* d_ws, size_t ws_size,
                              hipStream_t stream) {
  const float* x  = (const float*)d_in[0];
  const float* wq = (const float*)d_in[1];
  const float* sq = (const float*)d_in[2];
  const float* bq = (const float*)d_in[3];
  const float* wk = (const float*)d_in[4];
  const float* sk = (const float*)d_in[5];
  const float* bk = (const float*)d_in[6];
  const float* wv = (const float*)d_in[7];
  const float* sv = (const float*)d_in[8];
  const float* bv = (const float*)d_in[9];
  const float* wp = (const float*)d_in[10];
  const float* sp = (const float*)d_in[11];
  const float* bp = (const float*)d_in[12];
  float* out = (float*)d_out;

  // ws: x_t/o_t overlay @0 (8MB) | q_t @8M | k_t @12M | v_h @16M (8MB) |
  //     wqkv @24M | wph | ball
  char* ws = (char*)d_ws;
  u16*   x_t  = (u16*)(ws);
  u16*   q_t  = (u16*)(ws + (8u  << 20));
  u16*   k_t  = (u16*)(ws + (12u << 20));
  u16*   v_h  = (u16*)(ws + (16u << 20));
  u16*   wqkv = (u16*)(ws + (24u << 20));
  u16*   wph  = (u16*)(ws + (24u << 20) + (256u << 10));
  float* ball = (float*)(ws + (24u << 20) + (384u << 10));

  prep_fused<<<dim3(1216), dim3(256), 0, stream>>>(
      x, x_t, wq, sq, bq, wk, sk, bk, wv, sv, bv, wp, sp, bp, wqkv, wph, ball);
  conv_mfma<128, 0><<<dim3(8, 4, 16), dim3(256), 0, stream>>>(
      wqkv, x_t, ball, q_t, k_t, v_h, nullptr);
  attn_mfma<<<dim3(256), dim3(1024), 0, stream>>>(q_t, k_t, v_h, x_t /* o_t */);
  conv_mfma<64, 1><<<dim3(16, 2, 16), dim3(256), 0, stream>>>(
      wph, x_t /* o_t */, ball + 512, nullptr, nullptr, nullptr, out);
}

// Round 9
// 68.984 us; speedup vs baseline: 1.9405x; 1.4876x over previous
//
#include <hip/hip_runtime.h>

#define NTOT 1024
#define CIN  256
#define BATCH 16
#define NH   8
#define KD   16
#define DV   32
#define L2E  1.44269504088896340736f

typedef unsigned short u16;
typedef unsigned int   u32;
typedef __attribute__((ext_vector_type(2)))  _Float16 f16x2;
typedef __attribute__((ext_vector_type(8)))  _Float16 f16x8;
typedef __attribute__((ext_vector_type(16))) float    f32x16;

__device__ inline f16x8 as_f16x8(uint4 u) { return __builtin_bit_cast(f16x8, u); }
__device__ inline f16x2 as_f16x2(u32 u)   { return __builtin_bit_cast(f16x2, u); }
__device__ inline u32 pkrtz(float a, float b) {
  return __builtin_bit_cast(u32, __builtin_amdgcn_cvt_pkrtz(a, b));
}
__device__ inline u16 f2h(float x) {
  return __builtin_bit_cast(u16, (_Float16)x);
}
__device__ inline float fexp2(float x) {
#if __has_builtin(__builtin_amdgcn_exp2f)
  return __builtin_amdgcn_exp2f(x);              // raw v_exp_f32
#else
  float r; asm("v_exp_f32 %0, %1" : "=v"(r) : "v"(x)); return r;
#endif
}
__device__ inline float dot2acc(u32 p2, float c) {
#if __has_builtin(__builtin_amdgcn_fdot2)
  const f16x2 one2 = __builtin_bit_cast(f16x2, (u32)0x3C003C00u);
  return __builtin_amdgcn_fdot2(as_f16x2(p2), one2, c, false);
#else
  const f16x2 v = as_f16x2(p2);
  return c + (float)v[0] + (float)v[1];
#endif
}

// ---------------------------------------------------------------------------
// Fused prep: blocks [0,1024): x[b][c][n] fp32 -> x_t[b][n][c] fp16 (64x64
// LDS transpose).  Blocks [1024,1216): weight fp32->fp16 with BN scale folded
// (Q rows x log2e for exp2-domain softmax), 4 rows per block.
// ---------------------------------------------------------------------------
__global__ __launch_bounds__(256) void prep_fused(
    const float* __restrict__ X, u16* __restrict__ Xt,
    const float* __restrict__ wq, const float* __restrict__ sq, const float* __restrict__ bq,
    const float* __restrict__ wk, const float* __restrict__ sk, const float* __restrict__ bk,
    const float* __restrict__ wv, const float* __restrict__ sv, const float* __restrict__ bv,
    const float* __restrict__ wp, const float* __restrict__ sp, const float* __restrict__ bp,
    u16* __restrict__ wqkv, u16* __restrict__ wph, float* __restrict__ ball)
{
  __shared__ u16 T[64][64];
  const int bx = blockIdx.x;
  const int t  = threadIdx.x;
  if (bx < 1024) {
    const int n0 = (bx & 15) * 64;
    const int c0 = ((bx >> 4) & 3) * 64;
    const int b  = bx >> 6;
    #pragma unroll
    for (int rr = 0; rr < 4; ++rr) {
      const int c  = rr*16 + (t>>4);
      const int n4 = (t&15)*4;
      const float4 v = *(const float4*)&X[((size_t)b*CIN + c0 + c)*NTOT + n0 + n4];
      ushort4 r; r.x=f2h(v.x); r.y=f2h(v.y); r.z=f2h(v.z); r.w=f2h(v.w);
      *(ushort4*)&T[c][n4] = r;
    }
    __syncthreads();
    const int nl = t & 63;
    #pragma unroll
    for (int j = 0; j < 2; ++j) {
      const int oct = (t>>6)*2 + j;
      uint4 w;
      w.x = (u32)T[oct*8+0][nl] | ((u32)T[oct*8+1][nl] << 16);
      w.y = (u32)T[oct*8+2][nl] | ((u32)T[oct*8+3][nl] << 16);
      w.z = (u32)T[oct*8+4][nl] | ((u32)T[oct*8+5][nl] << 16);
      w.w = (u32)T[oct*8+6][nl] | ((u32)T[oct*8+7][nl] << 16);
      *(uint4*)&Xt[((size_t)b*NTOT + n0 + nl)*CIN + c0 + oct*8] = w;
    }
  } else {
    const int row = (bx - 1024)*4 + (t>>6);   // 0..767
    const int ln  = t & 63;
    const float* src; u16* dst; float sc, bi;
    if (row < 128)      { src = wq + (size_t)row*CIN;       sc = sq[row]*L2E;     bi = bq[row]*L2E;     dst = wqkv + (size_t)row*CIN; }
    else if (row < 256) { src = wk + (size_t)(row-128)*CIN; sc = sk[row-128];     bi = bk[row-128];     dst = wqkv + (size_t)row*CIN; }
    else if (row < 512) { src = wv + (size_t)(row-256)*CIN; sc = sv[row-256];     bi = bv[row-256];     dst = wqkv + (size_t)row*CIN; }
    else                { src = wp + (size_t)(row-512)*CIN; sc = sp[row-512];     bi = bp[row-512];     dst = wph + (size_t)(row-512)*CIN; }
    const float4 v = *(const float4*)&src[ln*4];
    ushort4 r;
    r.x = f2h(v.x*sc); r.y = f2h(v.y*sc); r.z = f2h(v.z*sc); r.w = f2h(v.w*sc);
    *(ushort4*)&dst[ln*4] = r;
    if (ln == 0) ball[row] = bi;
  }
}

// ---------------------------------------------------------------------------
// fp16 MFMA GEMM, BM=128, BN templated, 4 waves 2x2, double-buffered LDS
// (reg-staged).  MODE 0 epilogue -> attention-native layouts.  MODE 1 -> fp32.
// ---------------------------------------------------------------------------
template<int BN, int MODE>
__global__ __launch_bounds__(256) void conv_mfma(
    const u16* __restrict__ Wh, const u16* __restrict__ Bt,
    const float* __restrict__ ball,
    u16* __restrict__ q_t, u16* __restrict__ k_t, u16* __restrict__ v_h,
    float* __restrict__ outp)
{
  constexpr int FN = BN / 64;
  constexpr int NB = BN / 32;
  __shared__ u16 A_lds[2][128 * 64];
  __shared__ u16 B_lds[2][BN * 64];
  const int t    = threadIdx.x;
  const int lane = t & 63;
  const int w    = t >> 6;
  const int wm = w >> 1, wn = w & 1;
  const int g = lane >> 5, nl = lane & 31;
  const int n0 = blockIdx.x * BN;
  const int m0 = blockIdx.y * 128;
  const int b  = blockIdx.z;

  f32x16 acc[2][FN] = {};
  uint4 rA[4], rB[NB];

  #pragma unroll
  for (int r = 0; r < 4; ++r) {
    const int idx = t + r*256, row = idx >> 3, ch = idx & 7;
    rA[r] = *(const uint4*)&Wh[(size_t)(m0+row)*CIN + ch*8];
  }
  #pragma unroll
  for (int r = 0; r < NB; ++r) {
    const int idx = t + r*256, row = idx >> 3, ch = idx & 7;
    rB[r] = *(const uint4*)&Bt[((size_t)b*NTOT + n0 + row)*CIN + ch*8];
  }
  #pragma unroll
  for (int r = 0; r < 4; ++r) {
    const int idx = t + r*256, row = idx >> 3, ch = idx & 7;
    *(uint4*)&A_lds[0][row*64 + ((ch ^ (row&7))*8)] = rA[r];
  }
  #pragma unroll
  for (int r = 0; r < NB; ++r) {
    const int idx = t + r*256, row = idx >> 3, ch = idx & 7;
    *(uint4*)&B_lds[0][row*64 + ((ch ^ (row&7))*8)] = rB[r];
  }
  __syncthreads();

  for (int it = 0; it < 4; ++it) {
    const int cur = it & 1;
    if (it < 3) {
      const int c0 = (it+1)*64;
      #pragma unroll
      for (int r = 0; r < 4; ++r) {
        const int idx = t + r*256, row = idx >> 3, ch = idx & 7;
        rA[r] = *(const uint4*)&Wh[(size_t)(m0+row)*CIN + c0 + ch*8];
      }
      #pragma unroll
      for (int r = 0; r < NB; ++r) {
        const int idx = t + r*256, row = idx >> 3, ch = idx & 7;
        rB[r] = *(const uint4*)&Bt[((size_t)b*NTOT + n0 + row)*CIN + c0 + ch*8];
      }
    }
    #pragma unroll
    for (int ks = 0; ks < 4; ++ks) {
      const int ch = 2*ks + g;
      f16x8 a[2], bb[FN];
      #pragma unroll
      for (int fi = 0; fi < 2; ++fi) {
        const int row = wm*64 + fi*32 + nl;
        a[fi] = as_f16x8(*(const uint4*)&A_lds[cur][row*64 + ((ch ^ (row&7))*8)]);
      }
      #pragma unroll
      for (int fj = 0; fj < FN; ++fj) {
        const int row = wn*(BN/2) + fj*32 + nl;
        bb[fj] = as_f16x8(*(const uint4*)&B_lds[cur][row*64 + ((ch ^ (row&7))*8)]);
      }
      #pragma unroll
      for (int fi = 0; fi < 2; ++fi)
        #pragma unroll
        for (int fj = 0; fj < FN; ++fj)
          acc[fi][fj] = __builtin_amdgcn_mfma_f32_32x32x16_f16(a[fi], bb[fj], acc[fi][fj], 0, 0, 0);
    }
    if (it < 3) {
      #pragma unroll
      for (int r = 0; r < 4; ++r) {
        const int idx = t + r*256, row = idx >> 3, ch = idx & 7;
        *(uint4*)&A_lds[cur^1][row*64 + ((ch ^ (row&7))*8)] = rA[r];
      }
      #pragma unroll
      for (int r = 0; r < NB; ++r) {
        const int idx = t + r*256, row = idx >> 3, ch = idx & 7;
        *(uint4*)&B_lds[cur^1][row*64 + ((ch ^ (row&7))*8)] = rB[r];
      }
      __syncthreads();
    }
  }

  #pragma unroll
  for (int fi = 0; fi < 2; ++fi) {
    #pragma unroll
    for (int fj = 0; fj < FN; ++fj) {
      const int n = n0 + wn*(BN/2) + fj*32 + nl;
      #pragma unroll
      for (int q = 0; q < 4; ++q) {
        const int ob = m0 + wm*64 + fi*32 + 8*q + 4*g;   // wave-uniform
        const float v0 = acc[fi][fj][4*q+0] + ball[ob+0];
        const float v1 = acc[fi][fj][4*q+1] + ball[ob+1];
        const float v2 = acc[fi][fj][4*q+2] + ball[ob+2];
        const float v3 = acc[fi][fj][4*q+3] + ball[ob+3];
        if (MODE == 0) {
          if (ob < 128) {                       // Q rows
            const int h = ob >> 4, k0 = ob & 15;
            ushort4 r; r.x = f2h(v0); r.y = f2h(v1); r.z = f2h(v2); r.w = f2h(v3);
            *(ushort4*)&q_t[(((size_t)b*NH + h)*NTOT + n)*KD + k0] = r;
          } else if (ob < 256) {                // K rows -> plane layout
            const int oo = ob - 128;
            const int h = oo >> 4, k0 = oo & 15;
            const int plane = k0 >> 3, j0 = k0 & 7;
            ushort4 r; r.x = f2h(v0); r.y = f2h(v1); r.z = f2h(v2); r.w = f2h(v3);
            *(ushort4*)&k_t[((((size_t)b*NH + h)*2 + plane)*NTOT + n)*8 + j0] = r;
          } else {                              // V rows -> permuted layout
            const int oo = ob - 256;
            const int h = oo >> 5, d0 = oo & 31;
            const int mb = n >> 4, loc = n & 15;
            const int g2 = (loc >> 2) & 1;
            const int j  = (loc & 3) + ((loc >> 3) << 2);
            u16* vp = v_h + (((((size_t)b*NH + h)*64 + mb)*2 + g2)*32 + d0)*8 + j;
            vp[0*8] = f2h(v0);
            vp[1*8] = f2h(v1);
            vp[2*8] = f2h(v2);
            vp[3*8] = f2h(v3);
          }
        } else {
          float* op = outp + ((size_t)b*CIN + ob)*NTOT + n;
          op[0*NTOT] = v0; op[1*NTOT] = v1; op[2*NTOT] = v2; op[3*NTOT] = v3;
        }
      }
    }
  }
}

// ---------------------------------------------------------------------------
// fp16 MFMA attention, exp2 domain, no max-tracking, shuffle-free P->PV.
// 6-waves/SIMD build: block = 512 thr (8 waves) = 256 queries; LDS 48 KB
// (K resident 32 KB, V single-buffered 16 KB phase x4) -> 3 blocks/CU;
// __launch_bounds__(512,6) caps regs at 85 (live set ~75, no ILP pipeline
// -- R7/R8 proved deeper pipelines spill).  Grid 512 = qp*128 + bh so all
// 4 qparts of a bh share XCD bh%8 (K/V served from L2 after first touch).
// ---------------------------------------------------------------------------
__global__ __launch_bounds__(512, 6) void attn_mfma(
    const u16* __restrict__ Qt,  // [bh][n][16] fp16 (x log2e folded)
    const u16* __restrict__ Kt,  // [bh][plane2][m][8] fp16
    const u16* __restrict__ Vt,  // [bh][mb16][g2][d32][8] fp16
    u16* __restrict__ Ot)        // [b][n][256c] fp16 (relu'd)
{
  __shared__ u16 K_lds[2*NTOT*8];   // 32 KB  [plane][m][8]
  __shared__ u16 V_lds[1024*8];     // 16 KB  one 256-key phase
  const int t    = threadIdx.x;
  const int lane = t & 63;
  const int wave = t >> 6;          // 0..7
  const int bid  = blockIdx.x;
  const int bh   = bid & 127;
  const int qp   = bid >> 7;        // 0..3
  const int g = lane >> 5, nl = lane & 31;
  const int n0 = qp*256 + wave*32;

  const u16* Kh = Kt + (size_t)bh*(2*NTOT*8);
  const u16* Vh = Vt + (size_t)bh*(4096*8);
  const u16* Qh = Qt + (size_t)bh*(NTOT*KD);

  // stage K full (2048 uint4, 4/thread) + V phase 0 (1024 uint4, 2/thread)
  #pragma unroll
  for (int r = 0; r < 4; ++r) {
    const int uu = r*512 + t;
    *(uint4*)&K_lds[uu*8] = *(const uint4*)&Kh[uu*8];
  }
  #pragma unroll
  for (int r = 0; r < 2; ++r) {
    const int uu = r*512 + t;
    *(uint4*)&V_lds[uu*8] = *(const uint4*)&Vh[uu*8];
  }

  const f16x8 qf = as_f16x8(*(const uint4*)&Qh[(size_t)(n0+nl)*KD + g*8]);
  __syncthreads();

  const f32x16 fzero = {};
  f32x16 acc = {};
  float l0 = 0.f, l1 = 0.f;
  const char* Kb = (const char*)K_lds + g*16384 + nl*16;  // + step*512
  const char* Vb = (const char*)V_lds + g*512   + nl*16;  // + sl*2048 (+1024)

  #pragma unroll 1
  for (int ph = 0; ph < 4; ++ph) {
    #pragma unroll
    for (int sl = 0; sl < 8; ++sl) {
      const f16x8 kf = as_f16x8(*(const uint4*)(Kb + (ph*8 + sl)*512));
      const f32x16 s = __builtin_amdgcn_mfma_f32_32x32x16_f16(kf, qf, fzero, 0, 0, 0);

      uint4 pb0;
      {
        float p[8];
        #pragma unroll
        for (int r = 0; r < 8; ++r) p[r] = fexp2(s[r]);
        pb0.x = pkrtz(p[0], p[1]); pb0.y = pkrtz(p[2], p[3]);
        pb0.z = pkrtz(p[4], p[5]); pb0.w = pkrtz(p[6], p[7]);
        l0 = dot2acc(pb0.x, l0); l1 = dot2acc(pb0.y, l1);
        l0 = dot2acc(pb0.z, l0); l1 = dot2acc(pb0.w, l1);
      }
      uint4 pb1;
      {
        float p[8];
        #pragma unroll
        for (int r = 0; r < 8; ++r) p[r] = fexp2(s[8+r]);
        pb1.x = pkrtz(p[0], p[1]); pb1.y = pkrtz(p[2], p[3]);
        pb1.z = pkrtz(p[4], p[5]); pb1.w = pkrtz(p[6], p[7]);
        l0 = dot2acc(pb1.x, l0); l1 = dot2acc(pb1.y, l1);
        l0 = dot2acc(pb1.z, l0); l1 = dot2acc(pb1.w, l1);
      }

      const uint4 va0 = *(const uint4*)(Vb + sl*2048);
      const uint4 va1 = *(const uint4*)(Vb + sl*2048 + 1024);
      __builtin_amdgcn_s_setprio(1);
      acc = __builtin_amdgcn_mfma_f32_32x32x16_f16(as_f16x8(va0), as_f16x8(pb0), acc, 0, 0, 0);
      acc = __builtin_amdgcn_mfma_f32_32x32x16_f16(as_f16x8(va1), as_f16x8(pb1), acc, 0, 0, 0);
      __builtin_amdgcn_s_setprio(0);
    }
    if (ph < 3) {
      // swap in next 256-key V phase; barrier-bounded reg-stage
      __syncthreads();                   // all waves done reading this phase
      const int base = (ph + 1)*1024;
      const uint4 nv0 = *(const uint4*)&Vh[(base + t)*8];
      const uint4 nv1 = *(const uint4*)&Vh[(base + 512 + t)*8];
      *(uint4*)&V_lds[t*8]       = nv0;
      *(uint4*)&V_lds[(t+512)*8] = nv1;
      __syncthreads();                   // next phase visible
    }
  }

  const float lp = l0 + l1;
  const float lt = lp + __shfl_xor(lp, 32);
  const float rl = 1.0f / lt;
  const int b = bh >> 3, h = bh & 7;
  u16* op = Ot + ((size_t)b*NTOT + n0 + nl)*CIN + h*DV;
  #pragma unroll
  for (int q = 0; q < 4; ++q) {
    const float v0 = fmaxf(acc[4*q+0]*rl, 0.f);
    const float v1 = fmaxf(acc[4*q+1]*rl, 0.f);
    const float v2 = fmaxf(acc[4*q+2]*rl, 0.f);
    const float v3 = fmaxf(acc[4*q+3]*rl, 0.f);
    uint2 pk; pk.x = pkrtz(v0, v1); pk.y = pkrtz(v2, v3);
    *(uint2*)&op[8*q + 4*g] = pk;   // c = h*32 + 8q + 4g + {0..3}
  }
}

// ---------------------------------------------------------------------------
extern "C" void kernel_launch(void* const* d_in, const int* in_sizes, int n_in,
                              void* d_out, int out_size, void* d_ws, size_t ws_size,
                              hipStream_t stream) {
  const float* x  = (const float*)d_in[0];
  const float* wq = (const float*)d_in[1];
  const float* sq = (const float*)d_in[2];
  const float* bq = (const float*)d_in[3];
  const float* wk = (const float*)d_in[4];
  const float* sk = (const float*)d_in[5];
  const float* bk = (const float*)d_in[6];
  const float* wv = (const float*)d_in[7];
  const float* sv = (const float*)d_in[8];
  const float* bv = (const float*)d_in[9];
  const float* wp = (const float*)d_in[10];
  const float* sp = (const float*)d_in[11];
  const float* bp = (const float*)d_in[12];
  float* out = (float*)d_out;

  // ws: x_t/o_t overlay @0 (8MB) | q_t @8M | k_t @12M | v_h @16M (8MB) |
  //     wqkv @24M | wph | ball
  char* ws = (char*)d_ws;
  u16*   x_t  = (u16*)(ws);
  u16*   q_t  = (u16*)(ws + (8u  << 20));
  u16*   k_t  = (u16*)(ws + (12u << 20));
  u16*   v_h  = (u16*)(ws + (16u << 20));
  u16*   wqkv = (u16*)(ws + (24u << 20));
  u16*   wph  = (u16*)(ws + (24u << 20) + (256u << 10));
  float* ball = (float*)(ws + (24u << 20) + (384u << 10));

  prep_fused<<<dim3(1216), dim3(256), 0, stream>>>(
      x, x_t, wq, sq, bq, wk, sk, bk, wv, sv, bv, wp, sp, bp, wqkv, wph, ball);
  conv_mfma<128, 0><<<dim3(8, 4, 16), dim3(256), 0, stream>>>(
      wqkv, x_t, ball, q_t, k_t, v_h, nullptr);
  attn_mfma<<<dim3(512), dim3(512), 0, stream>>>(q_t, k_t, v_h, x_t /* o_t */);
  conv_mfma<64, 1><<<dim3(16, 2, 16), dim3(256), 0, stream>>>(
      wph, x_t /* o_t */, ball + 512, nullptr, nullptr, nullptr, out);
}

// Round 10
// 57.358 us; speedup vs baseline: 2.3339x; 1.2027x over previous
//
#include <hip/hip_runtime.h>

#define NTOT 1024
#define CIN  256
#define BATCH 16
#define NH   8
#define KD   16
#define DV   32
#define L2E  1.44269504088896340736f

typedef unsigned short u16;
typedef unsigned int   u32;
typedef __attribute__((ext_vector_type(2)))  _Float16 f16x2;
typedef __attribute__((ext_vector_type(8)))  _Float16 f16x8;
typedef __attribute__((ext_vector_type(16))) float    f32x16;

__device__ inline f16x8 as_f16x8(uint4 u) { return __builtin_bit_cast(f16x8, u); }
__device__ inline f16x2 as_f16x2(u32 u)   { return __builtin_bit_cast(f16x2, u); }
__device__ inline u32 pkrtz(float a, float b) {
  return __builtin_bit_cast(u32, __builtin_amdgcn_cvt_pkrtz(a, b));
}
__device__ inline u16 f2h(float x) {
  return __builtin_bit_cast(u16, (_Float16)x);
}
__device__ inline float fexp2(float x) {
#if __has_builtin(__builtin_amdgcn_exp2f)
  return __builtin_amdgcn_exp2f(x);              // raw v_exp_f32
#else
  float r; asm("v_exp_f32 %0, %1" : "=v"(r) : "v"(x)); return r;
#endif
}
__device__ inline float dot2acc(u32 p2, float c) {
#if __has_builtin(__builtin_amdgcn_fdot2)
  const f16x2 one2 = __builtin_bit_cast(f16x2, (u32)0x3C003C00u);
  return __builtin_amdgcn_fdot2(as_f16x2(p2), one2, c, false);
#else
  const f16x2 v = as_f16x2(p2);
  return c + (float)v[0] + (float)v[1];
#endif
}

// ---------------------------------------------------------------------------
// Fused prep: blocks [0,1024): x[b][c][n] fp32 -> x_t[b][n][c] fp16 (64x64
// LDS transpose).  Blocks [1024,1216): weight fp32->fp16 with BN scale folded
// (Q rows x log2e for exp2-domain softmax), 4 rows per block.
// ---------------------------------------------------------------------------
__global__ __launch_bounds__(256) void prep_fused(
    const float* __restrict__ X, u16* __restrict__ Xt,
    const float* __restrict__ wq, const float* __restrict__ sq, const float* __restrict__ bq,
    const float* __restrict__ wk, const float* __restrict__ sk, const float* __restrict__ bk,
    const float* __restrict__ wv, const float* __restrict__ sv, const float* __restrict__ bv,
    const float* __restrict__ wp, const float* __restrict__ sp, const float* __restrict__ bp,
    u16* __restrict__ wqkv, u16* __restrict__ wph, float* __restrict__ ball)
{
  __shared__ u16 T[64][64];
  const int bx = blockIdx.x;
  const int t  = threadIdx.x;
  if (bx < 1024) {
    const int n0 = (bx & 15) * 64;
    const int c0 = ((bx >> 4) & 3) * 64;
    const int b  = bx >> 6;
    #pragma unroll
    for (int rr = 0; rr < 4; ++rr) {
      const int c  = rr*16 + (t>>4);
      const int n4 = (t&15)*4;
      const float4 v = *(const float4*)&X[((size_t)b*CIN + c0 + c)*NTOT + n0 + n4];
      ushort4 r; r.x=f2h(v.x); r.y=f2h(v.y); r.z=f2h(v.z); r.w=f2h(v.w);
      *(ushort4*)&T[c][n4] = r;
    }
    __syncthreads();
    const int nl = t & 63;
    #pragma unroll
    for (int j = 0; j < 2; ++j) {
      const int oct = (t>>6)*2 + j;
      uint4 w;
      w.x = (u32)T[oct*8+0][nl] | ((u32)T[oct*8+1][nl] << 16);
      w.y = (u32)T[oct*8+2][nl] | ((u32)T[oct*8+3][nl] << 16);
      w.z = (u32)T[oct*8+4][nl] | ((u32)T[oct*8+5][nl] << 16);
      w.w = (u32)T[oct*8+6][nl] | ((u32)T[oct*8+7][nl] << 16);
      *(uint4*)&Xt[((size_t)b*NTOT + n0 + nl)*CIN + c0 + oct*8] = w;
    }
  } else {
    const int row = (bx - 1024)*4 + (t>>6);   // 0..767
    const int ln  = t & 63;
    const float* src; u16* dst; float sc, bi;
    if (row < 128)      { src = wq + (size_t)row*CIN;       sc = sq[row]*L2E;     bi = bq[row]*L2E;     dst = wqkv + (size_t)row*CIN; }
    else if (row < 256) { src = wk + (size_t)(row-128)*CIN; sc = sk[row-128];     bi = bk[row-128];     dst = wqkv + (size_t)row*CIN; }
    else if (row < 512) { src = wv + (size_t)(row-256)*CIN; sc = sv[row-256];     bi = bv[row-256];     dst = wqkv + (size_t)row*CIN; }
    else                { src = wp + (size_t)(row-512)*CIN; sc = sp[row-512];     bi = bp[row-512];     dst = wph + (size_t)(row-512)*CIN; }
    const float4 v = *(const float4*)&src[ln*4];
    ushort4 r;
    r.x = f2h(v.x*sc); r.y = f2h(v.y*sc); r.z = f2h(v.z*sc); r.w = f2h(v.w*sc);
    *(ushort4*)&dst[ln*4] = r;
    if (ln == 0) ball[row] = bi;
  }
}

// ---------------------------------------------------------------------------
// fp16 MFMA GEMM, BM=128, BN templated, 4 waves 2x2, double-buffered LDS
// (reg-staged).  MODE 0 epilogue -> attention-native layouts.  MODE 1 -> fp32.
// ---------------------------------------------------------------------------
template<int BN, int MODE>
__global__ __launch_bounds__(256) void conv_mfma(
    const u16* __restrict__ Wh, const u16* __restrict__ Bt,
    const float* __restrict__ ball,
    u16* __restrict__ q_t, u16* __restrict__ k_t, u16* __restrict__ v_h,
    float* __restrict__ outp)
{
  constexpr int FN = BN / 64;
  constexpr int NB = BN / 32;
  __shared__ u16 A_lds[2][128 * 64];
  __shared__ u16 B_lds[2][BN * 64];
  const int t    = threadIdx.x;
  const int lane = t & 63;
  const int w    = t >> 6;
  const int wm = w >> 1, wn = w & 1;
  const int g = lane >> 5, nl = lane & 31;
  const int n0 = blockIdx.x * BN;
  const int m0 = blockIdx.y * 128;
  const int b  = blockIdx.z;

  f32x16 acc[2][FN] = {};
  uint4 rA[4], rB[NB];

  #pragma unroll
  for (int r = 0; r < 4; ++r) {
    const int idx = t + r*256, row = idx >> 3, ch = idx & 7;
    rA[r] = *(const uint4*)&Wh[(size_t)(m0+row)*CIN + ch*8];
  }
  #pragma unroll
  for (int r = 0; r < NB; ++r) {
    const int idx = t + r*256, row = idx >> 3, ch = idx & 7;
    rB[r] = *(const uint4*)&Bt[((size_t)b*NTOT + n0 + row)*CIN + ch*8];
  }
  #pragma unroll
  for (int r = 0; r < 4; ++r) {
    const int idx = t + r*256, row = idx >> 3, ch = idx & 7;
    *(uint4*)&A_lds[0][row*64 + ((ch ^ (row&7))*8)] = rA[r];
  }
  #pragma unroll
  for (int r = 0; r < NB; ++r) {
    const int idx = t + r*256, row = idx >> 3, ch = idx & 7;
    *(uint4*)&B_lds[0][row*64 + ((ch ^ (row&7))*8)] = rB[r];
  }
  __syncthreads();

  for (int it = 0; it < 4; ++it) {
    const int cur = it & 1;
    if (it < 3) {
      const int c0 = (it+1)*64;
      #pragma unroll
      for (int r = 0; r < 4; ++r) {
        const int idx = t + r*256, row = idx >> 3, ch = idx & 7;
        rA[r] = *(const uint4*)&Wh[(size_t)(m0+row)*CIN + c0 + ch*8];
      }
      #pragma unroll
      for (int r = 0; r < NB; ++r) {
        const int idx = t + r*256, row = idx >> 3, ch = idx & 7;
        rB[r] = *(const uint4*)&Bt[((size_t)b*NTOT + n0 + row)*CIN + c0 + ch*8];
      }
    }
    #pragma unroll
    for (int ks = 0; ks < 4; ++ks) {
      const int ch = 2*ks + g;
      f16x8 a[2], bb[FN];
      #pragma unroll
      for (int fi = 0; fi < 2; ++fi) {
        const int row = wm*64 + fi*32 + nl;
        a[fi] = as_f16x8(*(const uint4*)&A_lds[cur][row*64 + ((ch ^ (row&7))*8)]);
      }
      #pragma unroll
      for (int fj = 0; fj < FN; ++fj) {
        const int row = wn*(BN/2) + fj*32 + nl;
        bb[fj] = as_f16x8(*(const uint4*)&B_lds[cur][row*64 + ((ch ^ (row&7))*8)]);
      }
      #pragma unroll
      for (int fi = 0; fi < 2; ++fi)
        #pragma unroll
        for (int fj = 0; fj < FN; ++fj)
          acc[fi][fj] = __builtin_amdgcn_mfma_f32_32x32x16_f16(a[fi], bb[fj], acc[fi][fj], 0, 0, 0);
    }
    if (it < 3) {
      #pragma unroll
      for (int r = 0; r < 4; ++r) {
        const int idx = t + r*256, row = idx >> 3, ch = idx & 7;
        *(uint4*)&A_lds[cur^1][row*64 + ((ch ^ (row&7))*8)] = rA[r];
      }
      #pragma unroll
      for (int r = 0; r < NB; ++r) {
        const int idx = t + r*256, row = idx >> 3, ch = idx & 7;
        *(uint4*)&B_lds[cur^1][row*64 + ((ch ^ (row&7))*8)] = rB[r];
      }
      __syncthreads();
    }
  }

  #pragma unroll
  for (int fi = 0; fi < 2; ++fi) {
    #pragma unroll
    for (int fj = 0; fj < FN; ++fj) {
      const int n = n0 + wn*(BN/2) + fj*32 + nl;
      #pragma unroll
      for (int q = 0; q < 4; ++q) {
        const int ob = m0 + wm*64 + fi*32 + 8*q + 4*g;   // wave-uniform
        const float v0 = acc[fi][fj][4*q+0] + ball[ob+0];
        const float v1 = acc[fi][fj][4*q+1] + ball[ob+1];
        const float v2 = acc[fi][fj][4*q+2] + ball[ob+2];
        const float v3 = acc[fi][fj][4*q+3] + ball[ob+3];
        if (MODE == 0) {
          if (ob < 128) {                       // Q rows
            const int h = ob >> 4, k0 = ob & 15;
            ushort4 r; r.x = f2h(v0); r.y = f2h(v1); r.z = f2h(v2); r.w = f2h(v3);
            *(ushort4*)&q_t[(((size_t)b*NH + h)*NTOT + n)*KD + k0] = r;
          } else if (ob < 256) {                // K rows -> plane layout
            const int oo = ob - 128;
            const int h = oo >> 4, k0 = oo & 15;
            const int plane = k0 >> 3, j0 = k0 & 7;
            ushort4 r; r.x = f2h(v0); r.y = f2h(v1); r.z = f2h(v2); r.w = f2h(v3);
            *(ushort4*)&k_t[((((size_t)b*NH + h)*2 + plane)*NTOT + n)*8 + j0] = r;
          } else {                              // V rows -> permuted layout
            const int oo = ob - 256;
            const int h = oo >> 5, d0 = oo & 31;
            const int mb = n >> 4, loc = n & 15;
            const int g2 = (loc >> 2) & 1;
            const int j  = (loc & 3) + ((loc >> 3) << 2);
            u16* vp = v_h + (((((size_t)b*NH + h)*64 + mb)*2 + g2)*32 + d0)*8 + j;
            vp[0*8] = f2h(v0);
            vp[1*8] = f2h(v1);
            vp[2*8] = f2h(v2);
            vp[3*8] = f2h(v3);
          }
        } else {
          float* op = outp + ((size_t)b*CIN + ob)*NTOT + n;
          op[0*NTOT] = v0; op[1*NTOT] = v1; op[2*NTOT] = v2; op[3*NTOT] = v3;
        }
      }
    }
  }
}

// ---------------------------------------------------------------------------
// fp16 MFMA attention (R5 structure restored): exp2 domain, no max-tracking,
// shuffle-free P->PV, 16 waves = one (b,h) x 512 queries, 96 KB LDS, one-step-
// ahead QK rotation (proven no-spill at ~52 VGPR).  R10 delta: each step is
// processed as two 8-wide half-streams (8 exp -> pack -> PV mfma), so PV0
// issues after half the trans work and exp-half-1 runs under PV0's latency.
// ---------------------------------------------------------------------------
__global__ __launch_bounds__(1024) void attn_mfma(
    const u16* __restrict__ Qt,  // [bh][n][16] fp16 (x log2e folded)
    const u16* __restrict__ Kt,  // [bh][plane2][m][8] fp16
    const u16* __restrict__ Vt,  // [bh][mb16][g2][d32][8] fp16
    u16* __restrict__ Ot)        // [b][n][256c] fp16 (relu'd)
{
  __shared__ u16 K_lds[2*NTOT*8];   // 32 KB
  __shared__ u16 V_lds[4096*8];     // 64 KB
  const int t    = threadIdx.x;
  const int lane = t & 63;
  const int wave = t >> 6;
  const int bh   = blockIdx.x >> 1;
  const int half = blockIdx.x & 1;
  const int g = lane >> 5, nl = lane & 31;
  const int n0 = half*512 + wave*32;

  const u16* Kh = Kt + (size_t)bh*(2*NTOT*8);
  const u16* Vh = Vt + (size_t)bh*(4096*8);
  const u16* Qh = Qt + (size_t)bh*(NTOT*KD);

  #pragma unroll
  for (int r = 0; r < 2; ++r) {
    const int uu = r*1024 + t;
    *(uint4*)&K_lds[uu*8] = *(const uint4*)&Kh[uu*8];
  }
  #pragma unroll
  for (int r = 0; r < 4; ++r) {
    const int uu = r*1024 + t;
    *(uint4*)&V_lds[uu*8] = *(const uint4*)&Vh[uu*8];
  }

  const f16x8 qf = as_f16x8(*(const uint4*)&Qh[(size_t)(n0+nl)*KD + g*8]);
  __syncthreads();

  const f32x16 fzero = {};
  f32x16 acc = {};
  float l0 = 0.f, l1 = 0.f, l2 = 0.f, l3 = 0.f;
  const char* Kb = (const char*)K_lds + g*16384 + nl*16;  // + step*512
  const char* Vb = (const char*)V_lds + g*512   + nl*16;  // + step*2048 (+1024)

  f16x8 kf  = as_f16x8(*(const uint4*)(Kb));
  uint4 va0 = *(const uint4*)(Vb);
  uint4 va1 = *(const uint4*)(Vb + 1024);
  f32x16 s_cur = __builtin_amdgcn_mfma_f32_32x32x16_f16(kf, qf, fzero, 0, 0, 0);

  #pragma unroll 2
  for (int st = 0; st < 31; ++st) {
    // next step's K frag + QK MFMA, issued before processing current scores
    const f16x8 kfn = as_f16x8(*(const uint4*)(Kb + (st+1)*512));
    __builtin_amdgcn_s_setprio(1);
    const f32x16 s_next = __builtin_amdgcn_mfma_f32_32x32x16_f16(kfn, qf, fzero, 0, 0, 0);
    __builtin_amdgcn_s_setprio(0);
    const uint4 nva0 = *(const uint4*)(Vb + (st+1)*2048);
    const uint4 nva1 = *(const uint4*)(Vb + (st+1)*2048 + 1024);

    // ---- half 0: m-slots 0..7 -> PV0 issues after only 8 exps ----
    {
      float p[8];
      #pragma unroll
      for (int r = 0; r < 8; ++r) p[r] = fexp2(s_cur[r]);
      uint4 pb0;
      pb0.x = pkrtz(p[0], p[1]); pb0.y = pkrtz(p[2], p[3]);
      pb0.z = pkrtz(p[4], p[5]); pb0.w = pkrtz(p[6], p[7]);
      l0 = dot2acc(pb0.x, l0); l1 = dot2acc(pb0.y, l1);
      l2 = dot2acc(pb0.z, l2); l3 = dot2acc(pb0.w, l3);
      __builtin_amdgcn_s_setprio(1);
      acc = __builtin_amdgcn_mfma_f32_32x32x16_f16(as_f16x8(va0), as_f16x8(pb0), acc, 0, 0, 0);
      __builtin_amdgcn_s_setprio(0);
    }
    // ---- half 1: m-slots 8..15 (exps overlap PV0's MFMA latency) ----
    {
      float p[8];
      #pragma unroll
      for (int r = 0; r < 8; ++r) p[r] = fexp2(s_cur[8+r]);
      uint4 pb1;
      pb1.x = pkrtz(p[0], p[1]); pb1.y = pkrtz(p[2], p[3]);
      pb1.z = pkrtz(p[4], p[5]); pb1.w = pkrtz(p[6], p[7]);
      l0 = dot2acc(pb1.x, l0); l1 = dot2acc(pb1.y, l1);
      l2 = dot2acc(pb1.z, l2); l3 = dot2acc(pb1.w, l3);
      __builtin_amdgcn_s_setprio(1);
      acc = __builtin_amdgcn_mfma_f32_32x32x16_f16(as_f16x8(va1), as_f16x8(pb1), acc, 0, 0, 0);
      __builtin_amdgcn_s_setprio(0);
    }
    s_cur = s_next; va0 = nva0; va1 = nva1;
  }
  { // last step (st = 31), no prefetch
    {
      float p[8];
      #pragma unroll
      for (int r = 0; r < 8; ++r) p[r] = fexp2(s_cur[r]);
      uint4 pb0;
      pb0.x = pkrtz(p[0], p[1]); pb0.y = pkrtz(p[2], p[3]);
      pb0.z = pkrtz(p[4], p[5]); pb0.w = pkrtz(p[6], p[7]);
      l0 = dot2acc(pb0.x, l0); l1 = dot2acc(pb0.y, l1);
      l2 = dot2acc(pb0.z, l2); l3 = dot2acc(pb0.w, l3);
      acc = __builtin_amdgcn_mfma_f32_32x32x16_f16(as_f16x8(va0), as_f16x8(pb0), acc, 0, 0, 0);
    }
    {
      float p[8];
      #pragma unroll
      for (int r = 0; r < 8; ++r) p[r] = fexp2(s_cur[8+r]);
      uint4 pb1;
      pb1.x = pkrtz(p[0], p[1]); pb1.y = pkrtz(p[2], p[3]);
      pb1.z = pkrtz(p[4], p[5]); pb1.w = pkrtz(p[6], p[7]);
      l0 = dot2acc(pb1.x, l0); l1 = dot2acc(pb1.y, l1);
      l2 = dot2acc(pb1.z, l2); l3 = dot2acc(pb1.w, l3);
      acc = __builtin_amdgcn_mfma_f32_32x32x16_f16(as_f16x8(va1), as_f16x8(pb1), acc, 0, 0, 0);
    }
  }

  const float lp = (l0 + l1) + (l2 + l3);
  const float lt = lp + __shfl_xor(lp, 32);
  const float rl = 1.0f / lt;
  const int b = bh >> 3, h = bh & 7;
  u16* op = Ot + ((size_t)b*NTOT + n0 + nl)*CIN + h*DV;
  #pragma unroll
  for (int q = 0; q < 4; ++q) {
    const float v0 = fmaxf(acc[4*q+0]*rl, 0.f);
    const float v1 = fmaxf(acc[4*q+1]*rl, 0.f);
    const float v2 = fmaxf(acc[4*q+2]*rl, 0.f);
    const float v3 = fmaxf(acc[4*q+3]*rl, 0.f);
    uint2 pk; pk.x = pkrtz(v0, v1); pk.y = pkrtz(v2, v3);
    *(uint2*)&op[8*q + 4*g] = pk;   // c = h*32 + 8q + 4g + {0..3}
  }
}

// ---------------------------------------------------------------------------
extern "C" void kernel_launch(void* const* d_in, const int* in_sizes, int n_in,
                              void* d_out, int out_size, void* d_ws, size_t ws_size,
                              hipStream_t stream) {
  const float* x  = (const float*)d_in[0];
  const float* wq = (const float*)d_in[1];
  const float* sq = (const float*)d_in[2];
  const float* bq = (const float*)d_in[3];
  const float* wk = (const float*)d_in[4];
  const float* sk = (const float*)d_in[5];
  const float* bk = (const float*)d_in[6];
  const float* wv = (const float*)d_in[7];
  const float* sv = (const float*)d_in[8];
  const float* bv = (const float*)d_in[9];
  const float* wp = (const float*)d_in[10];
  const float* sp = (const float*)d_in[11];
  const float* bp = (const float*)d_in[12];
  float* out = (float*)d_out;

  // ws: x_t/o_t overlay @0 (8MB) | q_t @8M | k_t @12M | v_h @16M (8MB) |
  //     wqkv @24M | wph | ball
  char* ws = (char*)d_ws;
  u16*   x_t  = (u16*)(ws);
  u16*   q_t  = (u16*)(ws + (8u  << 20));
  u16*   k_t  = (u16*)(ws + (12u << 20));
  u16*   v_h  = (u16*)(ws + (16u << 20));
  u16*   wqkv = (u16*)(ws + (24u << 20));
  u16*   wph  = (u16*)(ws + (24u << 20) + (256u << 10));
  float* ball = (float*)(ws + (24u << 20) + (384u << 10));

  prep_fused<<<dim3(1216), dim3(256), 0, stream>>>(
      x, x_t, wq, sq, bq, wk, sk, bk, wv, sv, bv, wp, sp, bp, wqkv, wph, ball);
  conv_mfma<128, 0><<<dim3(8, 4, 16), dim3(256), 0, stream>>>(
      wqkv, x_t, ball, q_t, k_t, v_h, nullptr);
  attn_mfma<<<dim3(256), dim3(1024), 0, stream>>>(q_t, k_t, v_h, x_t /* o_t */);
  conv_mfma<64, 1><<<dim3(16, 2, 16), dim3(256), 0, stream>>>(
      wph, x_t /* o_t */, ball + 512, nullptr, nullptr, nullptr, out);
}